// Round 7
// baseline (97.219 us; speedup 1.0000x reference)
//
#include <hip/hip_runtime.h>
#include <math.h>

#define PUPIL 256
#define N_BINS 8
#define BATCH 16

__constant__ int PHASE_NS_C[N_BINS] = {1024, 988, 952, 918, 886, 856, 828, 802};

typedef short bf16x8 __attribute__((ext_vector_type(8)));
typedef short bf16x4 __attribute__((ext_vector_type(4)));
typedef float f32x4  __attribute__((ext_vector_type(4)));
typedef int   i32x4  __attribute__((ext_vector_type(4)));

#define MFMA16(a, b, c) __builtin_amdgcn_mfma_f32_16x16x32_bf16((a), (b), (c), 0, 0, 0)

__device__ __forceinline__ short f2bf(float f) {   // RNE float->bf16
  unsigned u = __float_as_uint(f);
  u += 0x7FFFu + ((u >> 16) & 1u);
  return (short)(u >> 16);
}
__device__ __forceinline__ bf16x8 neg8(bf16x8 v) {
  i32x4 t = __builtin_bit_cast(i32x4, v);
  t ^= (int)0x80008000;
  return __builtin_bit_cast(bf16x8, t);
}

// ---------------------------------------------------------------------------
// PSF[u,v] = | sum_{y,x} P[y,x] W[y,u] W[x,v] |^2 ; W[n,k]=e^{-2pi i (k-32) n/N}
// R7: 2 kernels only (R4-R6 lesson: per-kernel launch/drain gaps + the fixed
// 42us ws-poison dominate; kernel math is ~2us).
//  K1 stage1: G^T[kv][y] = sum_x W[kv][x] P[y][x]. W A-frags computed on the
//     fly via __sincosf (exact int product (kv-32)*x <= 8160, fp32-exact);
//     (b==0,yc==0) blocks persist W rows to W_t for K2; also zeroes d_out.
//  K2 stage2: H^T[kv][ku] = sum_y G^T[kv][y] W[ku][y]; full (b,bin) per
//     block -> complete S in-block -> atomicAdd sed/S * |H|^2 into d_out.
// MFMA 16x16x32 bf16 (verified R4-R6): A[m=lane&15][k=quad*8+j] 16B contig,
// B-frag = B^T row, D: col(lane&15)=N-dim, row(quad*4+reg)=M-dim.
// ---------------------------------------------------------------------------

// stage1: grid (8 ychunk of 32, 8 bin, 16 b) = 1024 blocks; 4KB LDS.
__global__ __launch_bounds__(256, 4) void stage1(
    const float* __restrict__ opd, const float* __restrict__ obsc,
    const float* __restrict__ lambdas,
    short* __restrict__ Wr_t, short* __restrict__ Wi_t,
    short* __restrict__ Gr_t, short* __restrict__ Gi_t,
    float* __restrict__ out)
{
  const int tid = threadIdx.x;
  const int yb = blockIdx.x * 32, bin = blockIdx.y, b = blockIdx.z;
  const int bb = b * N_BINS + bin;
  const float w0 = 6.283185307179586f / lambdas[bin];
  const int   N  = PHASE_NS_C[bin];
  const float npiN = -6.283185307179586f / (float)N;
  const bool  storeW = (blockIdx.z == 0) && (blockIdx.x == 0);

  __shared__ short Pr[32 * 32], Pi[32 * 32];   // [y_local][x_local]

  // zero d_out: 1024 blocks x 64 floats = 65536
  if (tid < 64) {
    const int blin = blockIdx.x + 8 * (blockIdx.y + 8 * blockIdx.z);
    out[blin * 64 + tid] = 0.0f;
  }

  const int wave = tid >> 6, lane = tid & 63;
  const int lr = lane & 15, lq = lane >> 4;
  const int kv = wave * 16 + lr;
  const int kvm = kv - 32;

  f32x4 aR[2], aI[2];
  aR[0] = (f32x4)0.0f; aR[1] = (f32x4)0.0f;
  aI[0] = (f32x4)0.0f; aI[1] = (f32x4)0.0f;

  const int gy = tid >> 3;            // 0..31
  const int gx = (tid & 7) * 4;       // 0,4,..,28
  const float* orow = opd + ((size_t)b * PUPIL + yb + gy) * PUPIL;
  const float* brow = obsc + (size_t)(yb + gy) * PUPIL;

  for (int xc = 0; xc < 8; ++xc) {
    const int xb = xc * 32;
    // P pixels for LDS tile
    const float4 od = *(const float4*)(orow + xb + gx);
    const float4 ob = *(const float4*)(brow + xb + gx);
    bf16x4 vr, vi;
    {
      float s, c;
      __sincosf(w0 * od.x, &s, &c); vr[0] = f2bf(c * ob.x); vi[0] = f2bf(s * ob.x);
      __sincosf(w0 * od.y, &s, &c); vr[1] = f2bf(c * ob.y); vi[1] = f2bf(s * ob.y);
      __sincosf(w0 * od.z, &s, &c); vr[2] = f2bf(c * ob.z); vi[2] = f2bf(s * ob.z);
      __sincosf(w0 * od.w, &s, &c); vr[3] = f2bf(c * ob.w); vi[3] = f2bf(s * ob.w);
    }
    // W A-frag on the fly: W[kv][x], x = xb + lq*8 + j
    bf16x8 w_r, w_i;
    {
      const int x0 = xb + lq * 8;
      #pragma unroll
      for (int j = 0; j < 8; ++j) {
        float s, c;
        __sincosf((float)(kvm * (x0 + j)) * npiN, &s, &c);
        w_r[j] = f2bf(c);
        w_i[j] = f2bf(s);
      }
    }
    const bf16x8 nw_i = neg8(w_i);
    if (storeW) {
      *(bf16x8*)&Wr_t[((size_t)bin * 64 + kv) * 256 + xb + lq * 8] = w_r;
      *(bf16x8*)&Wi_t[((size_t)bin * 64 + kv) * 256 + xb + lq * 8] = w_i;
    }
    __syncthreads();                          // prior chunk's frag reads done
    *(bf16x4*)&Pr[gy * 32 + gx] = vr;
    *(bf16x4*)&Pi[gy * 32 + gx] = vi;
    __syncthreads();                          // P chunk visible

    for (int t = 0; t < 2; ++t) {
      const bf16x8 pr = *(const bf16x8*)&Pr[(t * 16 + lr) * 32 + lq * 8];
      const bf16x8 pi = *(const bf16x8*)&Pi[(t * 16 + lr) * 32 + lq * 8];
      aR[t] = MFMA16(w_r,  pr, aR[t]);
      aR[t] = MFMA16(nw_i, pi, aR[t]);
      aI[t] = MFMA16(w_r,  pi, aI[t]);
      aI[t] = MFMA16(w_i,  pr, aI[t]);
    }
  }

  #pragma unroll
  for (int t = 0; t < 2; ++t) {
    const int y = yb + t * 16 + lr;           // D col -> y
    #pragma unroll
    for (int r = 0; r < 4; ++r) {
      const int kvd = wave * 16 + lq * 4 + r; // D row -> kv
      const size_t o = ((size_t)bb * 64 + kvd) * 256 + y;
      Gr_t[o] = f2bf(aR[t][r]);
      Gi_t[o] = f2bf(aI[t][r]);
    }
  }
}

// stage2: grid (8 bin, 16 b) = 128 blocks. Full 64x64 H per block, complete
// S in-block, scaled atomicAdd into out (zeroed by stage1).
__global__ __launch_bounds__(256, 2) void stage2(
    const short* __restrict__ Wr_t, const short* __restrict__ Wi_t,
    const short* __restrict__ Gr_t, const short* __restrict__ Gi_t,
    const float* __restrict__ sed, float* __restrict__ out)
{
  const int tid = threadIdx.x;
  const int bin = blockIdx.x, b = blockIdx.y;
  const int bb = b * N_BINS + bin;

  __shared__ float red[4];

  const int wave = tid >> 6, lane = tid & 63;
  const int lr = lane & 15, lq = lane >> 4;

  f32x4 hR[4], hI[4];
  #pragma unroll
  for (int n = 0; n < 4; ++n) { hR[n] = (f32x4)0.0f; hI[n] = (f32x4)0.0f; }

  const short* grb = Gr_t + ((size_t)bb * 64 + wave * 16 + lr) * 256 + lq * 8;
  const short* gib = Gi_t + ((size_t)bb * 64 + wave * 16 + lr) * 256 + lq * 8;
  const size_t wbase = ((size_t)bin * 64 + lr) * 256 + lq * 8;

  for (int yc = 0; yc < 8; ++yc) {
    const int yb = yc * 32;
    const bf16x8 g_r  = *(const bf16x8*)(grb + yb);   // A-frag: G^T[kv][y]
    const bf16x8 g_i  = *(const bf16x8*)(gib + yb);
    const bf16x8 ng_i = neg8(g_i);
    for (int n = 0; n < 4; ++n) {
      const bf16x8 w_r = *(const bf16x8*)(Wr_t + wbase + (size_t)n * 16 * 256 + yb);
      const bf16x8 w_i = *(const bf16x8*)(Wi_t + wbase + (size_t)n * 16 * 256 + yb);
      hR[n] = MFMA16(g_r,  w_r, hR[n]);
      hR[n] = MFMA16(ng_i, w_i, hR[n]);
      hI[n] = MFMA16(g_r,  w_i, hI[n]);
      hI[n] = MFMA16(g_i,  w_r, hI[n]);
    }
  }

  float pv[4][4], lsum = 0.f;
  #pragma unroll
  for (int n = 0; n < 4; ++n)
    #pragma unroll
    for (int r = 0; r < 4; ++r) {
      pv[n][r] = hR[n][r] * hR[n][r] + hI[n][r] * hI[n][r];
      lsum += pv[n][r];
    }
  #pragma unroll
  for (int off = 32; off > 0; off >>= 1) lsum += __shfl_down(lsum, off);
  if (lane == 0) red[wave] = lsum;
  __syncthreads();
  const float S = red[0] + red[1] + red[2] + red[3];
  const float scale = sed[bin] / S;

  // D: col(lr)=ku-local per n-tile -> u = n*16+lr ; row(lq*4+r) -> v = wave*16+lq*4+r
  float* ob = out + (size_t)b * 4096;
  #pragma unroll
  for (int n = 0; n < 4; ++n) {
    const int u = n * 16 + lr;
    #pragma unroll
    for (int r = 0; r < 4; ++r) {
      const int v = wave * 16 + lq * 4 + r;
      atomicAdd(&ob[u * 64 + v], pv[n][r] * scale);
    }
  }
}

extern "C" void kernel_launch(void* const* d_in, const int* in_sizes, int n_in,
                              void* d_out, int out_size, void* d_ws, size_t ws_size,
                              hipStream_t stream) {
  const float* opd     = (const float*)d_in[0];
  const float* obsc    = (const float*)d_in[1];
  const float* lambdas = (const float*)d_in[2];
  const float* sed     = (const float*)d_in[3];
  float* out = (float*)d_out;

  // ws: Wr_t 256KB | Wi_t 256KB | Gr_t 4MB | Gi_t 4MB
  short* Wr_t = (short*)d_ws;
  short* Wi_t = Wr_t + (size_t)N_BINS * 64 * 256;
  short* Gr_t = Wi_t + (size_t)N_BINS * 64 * 256;
  short* Gi_t = Gr_t + (size_t)BATCH * N_BINS * 64 * 256;

  stage1<<<dim3(8, N_BINS, BATCH), 256, 0, stream>>>(opd, obsc, lambdas,
                                                     Wr_t, Wi_t, Gr_t, Gi_t, out);
  stage2<<<dim3(N_BINS, BATCH), 256, 0, stream>>>(Wr_t, Wi_t, Gr_t, Gi_t,
                                                  sed, out);
}